// Round 1
// baseline (1371.855 us; speedup 1.0000x reference)
//
#include <hip/hip_runtime.h>
#include <stdint.h>

#define N_ 2048
#define D_ 128
#define B_ 8
#define TILE 64
#define NT 32            // N_/TILE
#define NPAIRS 528       // NT*(NT+1)/2

// monotonic key: ascending uint order == ascending float order
__device__ __forceinline__ uint32_t fkey(float f) {
    uint32_t u = __float_as_uint(f);
    return (u & 0x80000000u) ? ~u : (u | 0x80000000u);
}
__device__ __forceinline__ float keyf(uint32_t k) {
    uint32_t u = (k & 0x80000000u) ? (k & 0x7fffffffu) : ~k;
    return __uint_as_float(u);
}

struct Tiles { float As[TILE][32]; float Bs[TILE][32]; };

// Computes 64x64 tile (ti,tj) of Xb*Xb^T. Thread t owns 4x4 outputs:
// rows ti*64 + ty*4 + r, cols tj*64 + tx*4 + c.  K staged in LDS chunks of 32,
// float4-vectorized, col4 XOR (row>>2)&7 swizzle -> <=2-way bank conflicts.
__device__ __forceinline__ void compute_tile(const float* __restrict__ Xb,
        int ti, int tj, Tiles& sm, float acc[4][4], int t)
{
    const int tx = t & 15, ty = t >> 4;
    #pragma unroll
    for (int r = 0; r < 4; ++r)
        #pragma unroll
        for (int c = 0; c < 4; ++c) acc[r][c] = 0.f;

    for (int kc = 0; kc < D_; kc += 32) {
        __syncthreads();   // protect LDS from previous chunk's readers
        #pragma unroll
        for (int q0 = 0; q0 < 512; q0 += 256) {
            int q = q0 + t;
            int row = q >> 3, c4 = q & 7;
            int sc4 = c4 ^ ((row >> 2) & 7);
            float4 va = *(const float4*)&Xb[(size_t)(ti*TILE + row)*D_ + kc + c4*4];
            *(float4*)&sm.As[row][sc4*4] = va;
            float4 vb = *(const float4*)&Xb[(size_t)(tj*TILE + row)*D_ + kc + c4*4];
            *(float4*)&sm.Bs[row][sc4*4] = vb;
        }
        __syncthreads();
        #pragma unroll
        for (int k4 = 0; k4 < 8; ++k4) {
            float4 a[4], bv[4];
            #pragma unroll
            for (int r = 0; r < 4; ++r)
                a[r] = *(const float4*)&sm.As[ty*4 + r][((k4 ^ (ty & 7)) * 4)];
            #pragma unroll
            for (int c = 0; c < 4; ++c)
                bv[c] = *(const float4*)&sm.Bs[tx*4 + c][((k4 ^ (tx & 7)) * 4)];
            #pragma unroll
            for (int r = 0; r < 4; ++r)
                #pragma unroll
                for (int c = 0; c < 4; ++c) {
                    acc[r][c] += a[r].x * bv[c].x;
                    acc[r][c] += a[r].y * bv[c].y;
                    acc[r][c] += a[r].z * bv[c].z;
                    acc[r][c] += a[r].w * bv[c].w;
                }
        }
    }
}

// MODE 0: histogram of key>>20 (4096 bins) via LDS hist, flush weighted to global
// MODE 1: for keys matching sel12, histogram (key>>4)&0xFFFF via global atomics
// MODE 2: masked MSE accumulate (both matrices) -> double atomic
template<int MODE>
__global__ __launch_bounds__(256) void sim_kernel(
    const float* __restrict__ Xin, const float* __restrict__ Xtg,
    uint32_t* __restrict__ hist12, uint32_t* __restrict__ hist16,
    const uint32_t* __restrict__ sel12,
    const float* __restrict__ thr, double* __restrict__ accum)
{
    __shared__ Tiles sm;
    __shared__ uint32_t lhist[(MODE == 0) ? 4096 : 1];
    __shared__ float wsum[4];

    const int t = threadIdx.x;
    const int b = blockIdx.y;
    const int m = (MODE == 2) ? 0 : blockIdx.z;

    if (MODE == 0) {
        #pragma unroll
        for (int i = 0; i < 16; ++i) lhist[t*16 + i] = 0;
        // first __syncthreads inside compute_tile orders this vs atomics
    }

    // decode linear pair index -> (ti, tj), ti <= tj
    int rem = blockIdx.x, ti = 0;
    while (true) { int len = NT - ti; if (rem < len) break; rem -= len; ++ti; }
    const int tj = ti + rem;
    const uint32_t w = (ti == tj) ? 1u : 2u;   // symmetry weight

    const float* X  = (m == 0) ? Xin : Xtg;
    const float* Xb = X + (size_t)b * N_ * D_;

    float acc[4][4];
    if (MODE != 2) {
        compute_tile(Xb, ti, tj, sm, acc, t);
        const int pair = m * B_ + b;
        if (MODE == 0) {
            #pragma unroll
            for (int r = 0; r < 4; ++r)
                #pragma unroll
                for (int c = 0; c < 4; ++c)
                    atomicAdd(&lhist[fkey(acc[r][c]) >> 20], 1u);
            __syncthreads();
            uint32_t* gh = hist12 + (size_t)pair * 4096;
            #pragma unroll
            for (int i = 0; i < 16; ++i) {
                uint32_t cnt = lhist[t*16 + i];
                if (cnt) atomicAdd(&gh[t*16 + i], cnt * w);
            }
        } else {
            const uint32_t sel = sel12[pair];
            uint32_t* gh = hist16 + (size_t)pair * 65536;
            #pragma unroll
            for (int r = 0; r < 4; ++r)
                #pragma unroll
                for (int c = 0; c < 4; ++c) {
                    uint32_t key = fkey(acc[r][c]);
                    if ((key >> 20) == sel) atomicAdd(&gh[(key >> 4) & 0xFFFFu], w);
                }
        }
    } else {
        float accT[4][4];
        compute_tile(Xb, ti, tj, sm, acc, t);
        const float* Yb = Xtg + (size_t)b * N_ * D_;
        compute_tile(Yb, ti, tj, sm, accT, t);
        const float thrI = thr[b], thrT = thr[B_ + b];
        float local = 0.f;
        #pragma unroll
        for (int r = 0; r < 4; ++r)
            #pragma unroll
            for (int c = 0; c < 4; ++c) {
                float aI = (acc[r][c]  >= thrI) ? acc[r][c]  : 0.f;
                float aT = (accT[r][c] >= thrT) ? accT[r][c] : 0.f;
                float d = aI - aT;
                local += d * d;
            }
        local *= (float)w;
        #pragma unroll
        for (int off = 32; off; off >>= 1) local += __shfl_down(local, off);
        const int lane = t & 63, wv = t >> 6;
        if (lane == 0) wsum[wv] = local;
        __syncthreads();
        if (t == 0) {
            double s = (double)wsum[0] + (double)wsum[1] + (double)wsum[2] + (double)wsum[3];
            atomicAdd(accum, s);
        }
    }
}

// Scan nbins histogram from top, find bin containing k-th largest.
// level 0: write sel12[pair], krem[pair].  level 1: write thr[pair].
__global__ __launch_bounds__(256) void select_kernel(
    const uint32_t* __restrict__ hist, int nbins,
    const int* __restrict__ kptr, const uint32_t* __restrict__ kremIn,
    const uint32_t* __restrict__ sel12In,
    uint32_t* __restrict__ selOut, uint32_t* __restrict__ kremOut,
    float* __restrict__ thrOut, int level)
{
    const int pair = blockIdx.x;
    const int t = threadIdx.x;
    const int chunk = nbins / 256;
    const uint32_t* h = hist + (size_t)pair * nbins;
    const uint64_t k0 = (level == 0) ? (uint64_t)kptr[0] : (uint64_t)kremIn[pair];

    __shared__ uint64_t csum[256];
    __shared__ uint64_t cpre[256];

    const int top = nbins - 1 - t * chunk;    // highest bin of my (descending) chunk
    uint64_t s = 0;
    for (int j = 0; j < chunk; ++j) s += h[top - j];
    csum[t] = s;
    __syncthreads();
    if (t == 0) {
        uint64_t run = 0;
        for (int i = 0; i < 256; ++i) { cpre[i] = run; run += csum[i]; }
    }
    __syncthreads();
    const uint64_t above = cpre[t];
    if (above < k0 && above + s >= k0) {
        uint64_t cum = above;
        for (int j = 0; j < chunk; ++j) {
            int bin = top - j;
            uint32_t c = h[bin];
            cum += c;
            if (cum >= k0) {
                if (level == 0) {
                    selOut[pair]  = (uint32_t)bin;
                    kremOut[pair] = (uint32_t)(k0 - (cum - c));
                } else {
                    uint32_t key = (sel12In[pair] << 20) | ((uint32_t)bin << 4);
                    thrOut[pair] = keyf(key);
                }
                break;
            }
        }
    }
}

__global__ void finalize_kernel(const double* __restrict__ accum, float* __restrict__ out) {
    out[0] = (float)(accum[0] / ((double)B_ * (double)N_ * (double)N_));
}

extern "C" void kernel_launch(void* const* d_in, const int* in_sizes, int n_in,
                              void* d_out, int out_size, void* d_ws, size_t ws_size,
                              hipStream_t stream)
{
    const float* Xin = (const float*)d_in[0];
    const float* Xtg = (const float*)d_in[1];
    const int*  kptr = (const int*)d_in[3];
    float* out = (float*)d_out;

    char* ws = (char*)d_ws;
    double*   accum  = (double*)ws;                                   // 8 B
    uint32_t* hist12 = (uint32_t*)(ws + 256);                         // 16*4096*4  = 256 KB
    uint32_t* hist16 = (uint32_t*)(ws + 256 + 16*4096*4);             // 16*65536*4 = 4 MB
    size_t off = 256 + (size_t)16*4096*4 + (size_t)16*65536*4;
    uint32_t* sel12 = (uint32_t*)(ws + off);
    uint32_t* krem  = (uint32_t*)(ws + off + 256);
    float*    thr   = (float*)   (ws + off + 512);
    if (ws_size < off + 1024) return;

    hipMemsetAsync(d_ws, 0, off, stream);   // zero accum + both histograms

    dim3 blk(256);
    sim_kernel<0><<<dim3(NPAIRS, B_, 2), blk, 0, stream>>>(Xin, Xtg, hist12, hist16, sel12, thr, accum);
    select_kernel<<<dim3(16), blk, 0, stream>>>(hist12, 4096, kptr, nullptr, nullptr,
                                                sel12, krem, thr, 0);
    sim_kernel<1><<<dim3(NPAIRS, B_, 2), blk, 0, stream>>>(Xin, Xtg, hist12, hist16, sel12, thr, accum);
    select_kernel<<<dim3(16), blk, 0, stream>>>(hist16, 65536, kptr, krem, sel12,
                                                nullptr, nullptr, thr, 1);
    sim_kernel<2><<<dim3(NPAIRS, B_, 1), blk, 0, stream>>>(Xin, Xtg, hist12, hist16, sel12, thr, accum);
    finalize_kernel<<<1, 1, 0, stream>>>(accum, out);
}